// Round 5
// baseline (13836.572 us; speedup 1.0000x reference)
//
#include <hip/hip_runtime.h>

#define NBLK  256
#define NTHR  512
#define TDEC  128
#define TENC  256
#define DIN   256
#define DENC  512
#define HHH   512
#define NG    1536
#define NK4   320
#define KB_X   0
#define KB_CTX 64
#define KB_H   192

// ws float offsets
#define OFF_CNT   0                      // 128*4 u32
#define OFF_U     512
#define OFF_ECTX  1536                   // 64*256
#define OFF_HG    17920                  // 64*512
#define OFF_CTXG  50688
#define OFF_RHG   83456
#define OFF_ZG    116224
#define OFF_WP    148992                 // 256*320*6*4 = 1,966,080 floats
#define WP_ELEMS  (NBLK*NK4*6*4)

#define TGT_A 256u
#define TGT_B 171u
#define TGT_C 86u

__device__ __forceinline__ float wave_sum(float v) {
#pragma unroll
    for (int o = 32; o; o >>= 1) v += __shfl_down(v, o, 64);
    return v;
}
__device__ __forceinline__ float wave_max(float v) {
#pragma unroll
    for (int o = 32; o; o >>= 1) v = fmaxf(v, __shfl_down(v, o, 64));
    return v;
}
__device__ __forceinline__ float ldA(float* p) {
    return __hip_atomic_load(p, __ATOMIC_RELAXED, __HIP_MEMORY_SCOPE_AGENT);
}
__device__ __forceinline__ void stA(float* p, float v) {
    __hip_atomic_store(p, v, __ATOMIC_RELAXED, __HIP_MEMORY_SCOPE_AGENT);
}
__device__ __forceinline__ void block_arrive(unsigned* c) {
    asm volatile("s_waitcnt vmcnt(0)" ::: "memory");
    __syncthreads();
    if (threadIdx.x == 0)
        __hip_atomic_fetch_add(c, 1u, __ATOMIC_RELAXED, __HIP_MEMORY_SCOPE_AGENT);
}
__device__ __forceinline__ void block_wait(unsigned* c, unsigned tgt) {
    if (threadIdx.x == 0) {
        while (__hip_atomic_load(c, __ATOMIC_RELAXED, __HIP_MEMORY_SCOPE_AGENT) < tgt)
            __builtin_amdgcn_s_sleep(1);
    }
    __syncthreads();
}

// ---------------- precompute ----------------
__global__ void k_u(const float* __restrict__ w1, const float* __restrict__ w2,
                    float* __restrict__ u) {
    int e = blockIdx.x;
    int lane = threadIdx.x;
    float p = 0.f;
#pragma unroll
    for (int k = lane; k < DENC; k += 64) p += w1[e*DENC + k] * w2[k];
    p = wave_sum(p);
    if (lane == 0) u[e] = p;
}

__global__ void k_ectx(const float* __restrict__ C, const float* __restrict__ u,
                       float* __restrict__ ectx) {
    int r = blockIdx.x*4 + (threadIdx.x >> 6);
    int lane = threadIdx.x & 63;
    const float* row = C + (size_t)r*DENC;
    const float* vc  = u + HHH;
    float p = 0.f;
#pragma unroll
    for (int k = 0; k < DENC/64; ++k) p += row[lane + k*64] * vc[lane + k*64];
    p = wave_sum(p);
    if (lane == 0) ectx[r] = p;
}

// pack: wp4[(blk*320 + k4)*6 + c] = float4 of W[k4*4..+4][col=blk*6+c]
__global__ void k_wpack(const float* __restrict__ Wx, const float* __restrict__ Wh,
                        float* __restrict__ wpo) {
    int id = blockIdx.x*256 + threadIdx.x;
    int e = id & 3;
    int q = id >> 2;
    int c = q % 6; q /= 6;
    int k4 = q % NK4;
    int blkq = q / NK4;
    int k = k4*4 + e;
    int col = blkq*6 + c;
    wpo[id] = (k < 768) ? Wx[(size_t)k*NG + col] : Wh[(size_t)(k-768)*NG + col];
}

// ---------------- main ----------------
// block = col-group (6 cols) + att-role (b_att = blk>>2, ds = blk&3). lane = batch.
__launch_bounds__(NTHR, 1)
__global__ void decoder(const float* __restrict__ inp, const float* __restrict__ C,
                        const float* __restrict__ bias, const float* __restrict__ wp,
                        float* __restrict__ out, float* __restrict__ ws)
{
    unsigned* cnt = (unsigned*)ws;
    float* u    = ws + OFF_U;
    float* ectx = ws + OFF_ECTX;
    float* hG   = ws + OFF_HG;
    float* ctxG = ws + OFF_CTXG;
    float* rhG  = ws + OFF_RHG;
    float* zG   = ws + OFF_ZG;

    const int tid  = threadIdx.x;
    const int lane = tid & 63;
    const int w    = tid >> 6;
    const int blk  = blockIdx.x;
    const int b_att = blk >> 2;
    const int ads   = blk & 3;
    const bool hasZR = (blk <= 170);
    const bool hasH  = (blk >= 170);

    __shared__ __align__(16) float abuf[64*65*4];   // 66.6 KB: [chunk][b] float4, pad 65
    __shared__ float sh_part[8][6][64];             // 12.3 KB
    __shared__ float sh_u[HHH];
    __shared__ float sh_att[TENC];
    __shared__ float sh_ectx[TENC];
    __shared__ float sh_cred[4][128];
    __shared__ float sh_hkeep[6][64];
    __shared__ float sh_red[8];

    float4* abuf4 = (float4*)abuf;
    const float4* wp4 = (const float4*)wp;

    int jcol[6], jp6[6];
    float bias6[6];
    unsigned zrmask = 0, hmask = 0;
#pragma unroll
    for (int c = 0; c < 6; ++c) {
        jcol[c] = blk*6 + c;
        jp6[c]  = jcol[c] & 511;
        if (jcol[c] < 1024) zrmask |= (1u << c); else hmask |= (1u << c);
        bias6[c] = (w == 0) ? bias[jcol[c]] : 0.f;
    }

    if (tid < HHH)  sh_u[tid] = u[tid];
    if (tid < TENC) sh_ectx[tid] = ectx[b_att*TENC + tid];
    __syncthreads();

    float acc[6];

    for (int t = 0; t < TDEC; ++t) {
#pragma unroll
        for (int c = 0; c < 6; ++c) acc[c] = bias6[c];

        // ---- stage x(t): [64 b][256] -> abuf[chunk][b] ----
        __syncthreads();
        for (int i = tid; i < 64*256; i += NTHR) {
            int jj = i & 255, bb = i >> 8;
            float v = inp[((size_t)bb*TDEC + t)*DIN + jj];
            abuf[((jj>>2)*65 + bb)*4 + (jj&3)] = v;
        }
        __syncthreads();

        // ---- x-dots (k4 0..64), all cols ----
#pragma unroll
        for (int kk = 0; kk < 8; ++kk) {
            const int cl = w*8 + kk;
            float4 a4 = abuf4[cl*65 + lane];
            const float4* wr = wp4 + ((size_t)blk*NK4 + KB_X + cl)*6;
#pragma unroll
            for (int c = 0; c < 6; ++c) {
                float4 wv = wr[c];
                acc[c] = fmaf(wv.x, a4.x, acc[c]);
                acc[c] = fmaf(wv.y, a4.y, acc[c]);
                acc[c] = fmaf(wv.z, a4.z, acc[c]);
                acc[c] = fmaf(wv.w, a4.w, acc[c]);
            }
        }

        // ---- wait h(t-1) ----
        if (t > 0) block_wait(&cnt[(t-1)*4 + 2], TGT_C);

        // ---- hkeep: h_prev for my 6 cols (direct) ----
        if (tid < 384) {
            int c = tid >> 6, bb = tid & 63;
            sh_hkeep[c][bb] = (t > 0) ? ldA(&hG[bb*HHH + jp6[c]]) : 0.f;
        }
        // ---- hd = u . h[b_att] ----
        {
            float p = (t > 0) ? sh_u[tid] * ldA(&hG[b_att*HHH + tid]) : 0.f;
            p = wave_sum(p);
            if (lane == 0) sh_red[w] = p;
        }
        __syncthreads();
        float hd = ((sh_red[0]+sh_red[1])+(sh_red[2]+sh_red[3]))
                 + ((sh_red[4]+sh_red[5])+(sh_red[6]+sh_red[7]));
        __syncthreads();

        // ---- softmax over relu(hd + ectx) (threads 0..255) ----
        float aex = 0.f;
        if (tid < TENC) {
            float e = fmaxf(hd + sh_ectx[tid], 0.f);
            float wm = wave_max(e);
            if (lane == 0) sh_red[w] = wm;
            aex = e;
        }
        __syncthreads();
        {
            float mx = fmaxf(fmaxf(sh_red[0], sh_red[1]), fmaxf(sh_red[2], sh_red[3]));
            if (tid < TENC) {
                aex = __expf(aex - mx);
                float s = wave_sum(aex);
                if (lane == 0) sh_red[w] = s;
            }
        }
        __syncthreads();
        if (tid < TENC) {
            float dn = (sh_red[0]+sh_red[1]) + (sh_red[2]+sh_red[3]);
            sh_att[tid] = aex / dn;
        }
        __syncthreads();

        // ---- ctx slice for (b_att, ads) + publish ----
        {
            int dp = tid & 127, q4 = tid >> 7;
            const float* Cb = C + ((size_t)b_att*TENC + q4*64)*DENC + ads*128 + dp;
            float a = 0.f;
#pragma unroll 8
            for (int q = 0; q < 64; ++q) a = fmaf(sh_att[q4*64 + q], Cb[(size_t)q*DENC], a);
            sh_cred[q4][dp] = a;
        }
        __syncthreads();
        if (tid < 128) stA(&ctxG[b_att*HHH + ads*128 + tid],
                           ((sh_cred[0][tid]+sh_cred[1][tid])+(sh_cred[2][tid]+sh_cred[3][tid])));
        block_arrive(&cnt[t*4 + 0]);        // event A

        // ---- H phase (z/r cols): k4 192..320 over h_prev ----
        if (hasZR && t > 0) {
            for (int hf = 0; hf < 2; ++hf) {
                for (int i = tid; i < 64*256; i += NTHR) {
                    int jj = i & 255, bb = i >> 8;
                    float v = ldA(&hG[bb*HHH + hf*256 + jj]);
                    abuf[((jj>>2)*65 + bb)*4 + (jj&3)] = v;
                }
                __syncthreads();
#pragma unroll
                for (int kk = 0; kk < 8; ++kk) {
                    const int cl = w*8 + kk;
                    float4 a4 = abuf4[cl*65 + lane];
                    const float4* wr = wp4 + ((size_t)blk*NK4 + KB_H + hf*64 + cl)*6;
#pragma unroll
                    for (int c = 0; c < 6; ++c) {
                        if (zrmask & (1u << c)) {
                            float4 wv = wr[c];
                            acc[c] = fmaf(wv.x, a4.x, acc[c]);
                            acc[c] = fmaf(wv.y, a4.y, acc[c]);
                            acc[c] = fmaf(wv.z, a4.z, acc[c]);
                            acc[c] = fmaf(wv.w, a4.w, acc[c]);
                        }
                    }
                }
                __syncthreads();
            }
        }

        // ---- wait ctx; CTX phase (all cols): k4 64..192 ----
        block_wait(&cnt[t*4 + 0], TGT_A);
        for (int hf = 0; hf < 2; ++hf) {
            for (int i = tid; i < 64*256; i += NTHR) {
                int jj = i & 255, bb = i >> 8;
                float v = ldA(&ctxG[bb*HHH + hf*256 + jj]);
                abuf[((jj>>2)*65 + bb)*4 + (jj&3)] = v;
            }
            __syncthreads();
#pragma unroll
            for (int kk = 0; kk < 8; ++kk) {
                const int cl = w*8 + kk;
                float4 a4 = abuf4[cl*65 + lane];
                const float4* wr = wp4 + ((size_t)blk*NK4 + KB_CTX + hf*64 + cl)*6;
#pragma unroll
                for (int c = 0; c < 6; ++c) {
                    float4 wv = wr[c];
                    acc[c] = fmaf(wv.x, a4.x, acc[c]);
                    acc[c] = fmaf(wv.y, a4.y, acc[c]);
                    acc[c] = fmaf(wv.z, a4.z, acc[c]);
                    acc[c] = fmaf(wv.w, a4.w, acc[c]);
                }
            }
            __syncthreads();
        }

        // ---- reduce + finish z/r; publish zG, rhG ----
        if (hasZR) {
#pragma unroll
            for (int c = 0; c < 6; ++c) sh_part[w][c][lane] = acc[c];
            __syncthreads();
            if (tid < 384) {
                int c = tid >> 6, bb = tid & 63;
                if (jcol[c] < 1024) {
                    float s = 0.f;
#pragma unroll
                    for (int ww = 0; ww < 8; ++ww) s += sh_part[ww][c][bb];
                    float g = 1.f / (1.f + __expf(-s));
                    if (jcol[c] < 512) stA(&zG[bb*HHH + jcol[c]], g);
                    else               stA(&rhG[bb*HHH + jp6[c]], g * sh_hkeep[c][bb]);
                }
            }
            block_arrive(&cnt[t*4 + 1]);    // event B
        }

        // ---- RH phase + finish h (h-gate blocks) ----
        if (hasH) {
            block_wait(&cnt[t*4 + 1], TGT_B);
            for (int hf = 0; hf < 2; ++hf) {
                for (int i = tid; i < 64*256; i += NTHR) {
                    int jj = i & 255, bb = i >> 8;
                    float v = ldA(&rhG[bb*HHH + hf*256 + jj]);
                    abuf[((jj>>2)*65 + bb)*4 + (jj&3)] = v;
                }
                __syncthreads();
#pragma unroll
                for (int kk = 0; kk < 8; ++kk) {
                    const int cl = w*8 + kk;
                    float4 a4 = abuf4[cl*65 + lane];
                    const float4* wr = wp4 + ((size_t)blk*NK4 + KB_H + hf*64 + cl)*6;
#pragma unroll
                    for (int c = 0; c < 6; ++c) {
                        if (hmask & (1u << c)) {
                            float4 wv = wr[c];
                            acc[c] = fmaf(wv.x, a4.x, acc[c]);
                            acc[c] = fmaf(wv.y, a4.y, acc[c]);
                            acc[c] = fmaf(wv.z, a4.z, acc[c]);
                            acc[c] = fmaf(wv.w, a4.w, acc[c]);
                        }
                    }
                }
                __syncthreads();
            }
#pragma unroll
            for (int c = 0; c < 6; ++c) sh_part[w][c][lane] = acc[c];
            __syncthreads();
            if (tid < 384) {
                int c = tid >> 6, bb = tid & 63;
                if (jcol[c] >= 1024) {
                    float s = 0.f;
#pragma unroll
                    for (int ww = 0; ww < 8; ++ww) s += sh_part[ww][c][bb];
                    float z  = ldA(&zG[bb*HHH + jp6[c]]);
                    float hh = tanhf(s);
                    float hp = sh_hkeep[c][bb];
                    float hn = z*hp + (1.f - z)*hh;
                    stA(&hG[bb*HHH + jp6[c]], hn);
                    out[((size_t)bb*TDEC + t)*HHH + jp6[c]] = hn;
                }
            }
            block_arrive(&cnt[t*4 + 2]);    // event C
        }
    }
}

extern "C" void kernel_launch(void* const* d_in, const int* in_sizes, int n_in,
                              void* d_out, int out_size, void* d_ws, size_t ws_size,
                              hipStream_t stream) {
    const float* inputs = (const float*)d_in[0];
    const float* C      = (const float*)d_in[1];
    const float* w1     = (const float*)d_in[2];
    const float* w2     = (const float*)d_in[3];
    const float* Wx     = (const float*)d_in[4];
    const float* Wh     = (const float*)d_in[5];
    const float* bias   = (const float*)d_in[6];
    float* out = (float*)d_out;
    float* ws  = (float*)d_ws;

    hipMemsetAsync(ws, 0, 128*4*sizeof(unsigned), stream);

    k_u    <<<1024, 64,  0, stream>>>(w1, w2, ws + OFF_U);
    k_ectx <<<(64*TENC)/4, 256, 0, stream>>>(C, ws + OFF_U, ws + OFF_ECTX);
    k_wpack<<<WP_ELEMS/256, 256, 0, stream>>>(Wx, Wh, ws + OFF_WP);
    decoder<<<NBLK, NTHR, 0, stream>>>(inputs, C, bias, ws + OFF_WP, out, ws);
}

// Round 9
// 3252.541 us; speedup vs baseline: 4.2541x; 4.2541x over previous
//
#include <hip/hip_runtime.h>

#define NBLK  256
#define NTHR  384
#define TDEC  128
#define TENC  256
#define DIN   256
#define DENC  512
#define HHH   512
#define NG    1536
#define KTOT  1280
#define NK4   320
#define NCOL  384          // 3 gates * 128 cols per js slice

// ws float offsets (same proven layout as round 4; total 8.56 MB)
#define OFF_CNT   0                       // 128*3*64 u32 = 24576
#define OFF_HDOT  24576                   // 128*64*4 f32 = 32768
#define OFF_U     57344                   // 1024
#define OFF_ECTX  58368                   // 64*256 = 16384
#define OFF_HG    74752                   // 64*512
#define OFF_CTXG  107520                  // 64*512
#define OFF_RHG   140288                  // 64*512
#define OFF_WP    173056                  // pack: 4*320*384*4 = 1,966,080 elems
#define WP_ELEMS  (4*NK4*NCOL*4)

// ---------------- small helpers ----------------
__device__ __forceinline__ float wave_sum(float v) {
#pragma unroll
    for (int o = 32; o; o >>= 1) v += __shfl_down(v, o, 64);
    return v;
}
__device__ __forceinline__ float wave_max(float v) {
#pragma unroll
    for (int o = 32; o; o >>= 1) v = fmaxf(v, __shfl_down(v, o, 64));
    return v;
}
__device__ __forceinline__ float ldA(float* p) {
    return __hip_atomic_load(p, __ATOMIC_RELAXED, __HIP_MEMORY_SCOPE_AGENT);
}
__device__ __forceinline__ void stA(float* p, float v) {
    __hip_atomic_store(p, v, __ATOMIC_RELAXED, __HIP_MEMORY_SCOPE_AGENT);
}
// drain THIS wave's outstanding vector-memory ops (stores included).
// Every wave that published data must execute this BEFORE the barrier that
// precedes the arrive — __syncthreads orders execution, not store visibility.
__device__ __forceinline__ void drain_stores() {
    asm volatile("s_waitcnt vmcnt(0)" ::: "memory");
}
__device__ __forceinline__ void arrive(unsigned* c) {
    asm volatile("s_waitcnt vmcnt(0)" ::: "memory");
    __hip_atomic_fetch_add(c, 1u, __ATOMIC_RELAXED, __HIP_MEMORY_SCOPE_AGENT);
}
__device__ __forceinline__ void wait4(unsigned* c) {
    while (__hip_atomic_load(c, __ATOMIC_RELAXED, __HIP_MEMORY_SCOPE_AGENT) < 4u)
        __builtin_amdgcn_s_sleep(2);
}
__device__ __forceinline__ float blo(unsigned u) { return __uint_as_float(u << 16); }
__device__ __forceinline__ float bhi(unsigned u) { return __uint_as_float(u & 0xffff0000u); }
__device__ __forceinline__ unsigned short f2bf(float f) {
    unsigned u = __float_as_uint(f);
    u += 0x7fffu + ((u >> 16) & 1u);
    return (unsigned short)(u >> 16);
}

// thread's partial dot over k4 in [k4lo,k4hi): weight elem (k4, c), acts a4[k4-aoff]
template<bool BF>
__device__ __forceinline__ float dotrange(const void* wp, size_t base, int c,
                                          int k4lo, int k4hi, const float4* a4,
                                          int aoff, float acc) {
    if (BF) {
        const uint2* w = (const uint2*)wp + base + c;
#pragma unroll 8
        for (int k4 = k4lo; k4 < k4hi; ++k4) {
            uint2 uu = w[(size_t)k4 * NCOL];
            float4 a = a4[k4 - aoff];
            acc = fmaf(blo(uu.x), a.x, acc);
            acc = fmaf(bhi(uu.x), a.y, acc);
            acc = fmaf(blo(uu.y), a.z, acc);
            acc = fmaf(bhi(uu.y), a.w, acc);
        }
    } else {
        const float4* w = (const float4*)wp + base + c;
#pragma unroll 8
        for (int k4 = k4lo; k4 < k4hi; ++k4) {
            float4 wv = w[(size_t)k4 * NCOL];
            float4 a = a4[k4 - aoff];
            acc = fmaf(wv.x, a.x, acc);
            acc = fmaf(wv.y, a.y, acc);
            acc = fmaf(wv.z, a.z, acc);
            acc = fmaf(wv.w, a.w, acc);
        }
    }
    return acc;
}

// ---------------- precompute kernels ----------------
__global__ void k_u(const float* __restrict__ w1, const float* __restrict__ w2,
                    float* __restrict__ u) {
    int e = blockIdx.x;
    int lane = threadIdx.x;
    float p = 0.f;
#pragma unroll
    for (int k = lane; k < DENC; k += 64) p += w1[e*DENC + k] * w2[k];
    p = wave_sum(p);
    if (lane == 0) u[e] = p;
}

__global__ void k_ectx(const float* __restrict__ C, const float* __restrict__ u,
                       float* __restrict__ ectx) {
    int r = blockIdx.x*4 + (threadIdx.x >> 6);
    int lane = threadIdx.x & 63;
    const float* row = C + (size_t)r*DENC;
    const float* vc  = u + HHH;
    float p = 0.f;
#pragma unroll
    for (int k = 0; k < DENC/64; ++k) p += row[lane + k*64] * vc[lane + k*64];
    p = wave_sum(p);
    if (lane == 0) ectx[r] = p;
}

// K-major pack: layout [js][k4][c][e], k=k4*4+e, col = (c>>7)*512 + js*128 + (c&127)
template<bool BF>
__global__ void k_wpack(const float* __restrict__ Wx, const float* __restrict__ Wh,
                        void* __restrict__ wp) {
    int id = blockIdx.x*256 + threadIdx.x;      // < WP_ELEMS
    int e = id & 3;
    int q = id >> 2;
    int c = q % NCOL;
    q /= NCOL;
    int k4 = q % NK4;
    int js = q / NK4;
    int k = k4*4 + e;
    int col = (c >> 7)*512 + js*128 + (c & 127);
    float v = (k < 768) ? Wx[(size_t)k*NG + col] : Wh[(size_t)(k-768)*NG + col];
    if (BF) ((unsigned short*)wp)[id] = f2bf(v);
    else    ((float*)wp)[id] = v;
}

// ---------------- main kernel ----------------
// 256 blocks: b = blk>>2, js = blk&3. Thread c: gate = c>>7 (0=z,1=r,2=h), jp = c&127.
template<bool BF>
__launch_bounds__(NTHR, 1)
__global__ void decoder(const float* __restrict__ inp, const float* __restrict__ C,
                        const float* __restrict__ bias, const void* __restrict__ wpv,
                        const float* __restrict__ u, float* __restrict__ ectx_g,
                        float* __restrict__ out, float* __restrict__ ws) {
    unsigned* cnt = (unsigned*)ws;
    float* hdotP = ws + OFF_HDOT;
    float* hG    = ws + OFF_HG;
    float* ctxG  = ws + OFF_CTXG;
    float* rhG   = ws + OFF_RHG;

    const int tid = threadIdx.x;
    const int w   = tid >> 6;
    const int b   = blockIdx.x >> 2;
    const int js  = blockIdx.x & 3;
    const int c    = tid;
    const int gate = c >> 7;
    const int jp   = c & 127;

    __shared__ float sh_C[TENC*128];              // 131 KB: fp32 C slice [q][dp]
    __shared__ __align__(16) float sh_kx[KTOT];   // [0,256)=x  [256,768)=ctx  [768,1280)=h_prev
    __shared__ __align__(16) float sh_rh[HHH];
    __shared__ float sh_att[TENC];
    __shared__ float sh_ectx[TENC];
    __shared__ float sh_u[128];
    __shared__ float sh_z[128];
    __shared__ float sh_cred[2][128];
    __shared__ float sh_red[8];
    __shared__ float sh_scal;

    const float4* kx4 = (const float4*)sh_kx;
    const float4* rh4 = (const float4*)sh_rh;
    const size_t wbase = (size_t)js * NK4 * NCOL;   // in float4/uint2 units

    // one-time staging: fp32 C slice (coalesced rows), ectx, u-slice
    for (int i = tid; i < TENC*128; i += NTHR) {
        int q = i >> 7, dp = i & 127;
        sh_C[i] = C[((size_t)b*TENC + q)*DENC + js*128 + dp];
    }
    if (tid < TENC) sh_ectx[tid] = ectx_g[b*TENC + tid];
    if (tid >= 256) sh_u[tid - 256] = u[js*128 + (tid - 256)];
    const float bias_c = bias[gate*512 + js*128 + jp];

    for (int t = 0; t < TDEC; ++t) {
        // ----- stage x_t (independent of events) -----
        __syncthreads();
        if (tid < DIN) sh_kx[tid] = inp[((size_t)b*TDEC + t)*DIN + tid];
        __syncthreads();

        // ----- x-part dots: k4 [0,64) for all cols -----
        float acc = dotrange<BF>(wpv, wbase, c, 0, 64, kx4, 0, bias_c);

        // ----- waitC(t-1): h_prev + hdot -----
        if (t > 0) {
            if (tid == 0) {
                wait4(&cnt[((t-1)*3 + 2)*64 + b]);
                float s0 = ldA(&hdotP[(t-1)*256 + b*4 + 0]);
                float s1 = ldA(&hdotP[(t-1)*256 + b*4 + 1]);
                float s2 = ldA(&hdotP[(t-1)*256 + b*4 + 2]);
                float s3 = ldA(&hdotP[(t-1)*256 + b*4 + 3]);
                sh_scal = (s0 + s1) + (s2 + s3);
            }
            __syncthreads();
            for (int i = tid; i < HHH; i += NTHR) sh_kx[768 + i] = ldA(&hG[b*HHH + i]);
        } else {
            if (tid == 0) sh_scal = 0.f;
            for (int i = tid; i < HHH; i += NTHR) sh_kx[768 + i] = 0.f;
        }
        __syncthreads();
        const float hd = sh_scal;

        // ----- attention softmax (threads 0..255, waves 0..3) -----
        if (tid < TENC) {
            float e = fmaxf(hd + sh_ectx[tid], 0.f);
            float wm = wave_max(e);
            if ((tid & 63) == 0) sh_red[w] = wm;
            __syncthreads();
            float mx = fmaxf(fmaxf(sh_red[0], sh_red[1]), fmaxf(sh_red[2], sh_red[3]));
            float ex = __expf(e - mx);
            float wse = wave_sum(ex);
            __syncthreads();
            if ((tid & 63) == 0) sh_red[w] = wse;
            __syncthreads();
            float dn = sh_red[0] + sh_red[1] + sh_red[2] + sh_red[3];
            sh_att[tid] = ex / dn;
        } else {
            __syncthreads(); __syncthreads(); __syncthreads();
        }
        __syncthreads();

        // ----- ctx slice from LDS fp32 C: ctx[js*128+dp] = sum_q att[q]*C[q][dp] -----
        if (tid < TENC) {
            const int dp = tid & 127, hf = tid >> 7;
            const float* Cl = sh_C + (size_t)hf*128*128 + dp;
            float a = 0.f;
#pragma unroll 8
            for (int q = 0; q < 128; ++q)
                a = fmaf(sh_att[hf*128 + q], Cl[(size_t)q*128], a);
            sh_cred[hf][dp] = a;
        }
        __syncthreads();
        if (tid < 128) stA(&ctxG[b*HHH + js*128 + tid], sh_cred[0][tid] + sh_cred[1][tid]);
        drain_stores();                                     // ALL waves drain ctx stores
        __syncthreads();
        if (tid == 0) arrive(&cnt[(t*3 + 0)*64 + b]);       // event A: ctx slice ready

        // ----- h-part dots: k4 [192,320) for z,r cols -----
        if (t > 0 && c < 256)
            acc = dotrange<BF>(wpv, wbase, c, 192, 320, kx4, 0, acc);

        // ----- waitA: stage full ctx, ctx-part dots k4 [64,192) -----
        if (tid == 0) wait4(&cnt[(t*3 + 0)*64 + b]);
        __syncthreads();
        for (int i = tid; i < HHH; i += NTHR) sh_kx[256 + i] = ldA(&ctxG[b*HHH + i]);
        __syncthreads();
        acc = dotrange<BF>(wpv, wbase, c, 64, 192, kx4, 0, acc);

        // ----- z, r finish; publish rh -----
        if (gate == 0) {
            sh_z[jp] = 1.f / (1.f + __expf(-acc));
        } else if (gate == 1) {
            float r = 1.f / (1.f + __expf(-acc));
            stA(&rhG[b*HHH + js*128 + jp], r * sh_kx[768 + js*128 + jp]);
        }
        drain_stores();                                     // ALL waves drain rh stores
        __syncthreads();
        if (tid == 0) arrive(&cnt[(t*3 + 1)*64 + b]);       // event B: rh slice ready

        // ----- waitB: stage rh, rh-part dots k4 [192,320) for gate-h cols -----
        if (tid == 0) wait4(&cnt[(t*3 + 1)*64 + b]);
        __syncthreads();
        for (int i = tid; i < HHH; i += NTHR) sh_rh[i] = ldA(&rhG[b*HHH + i]);
        __syncthreads();

        if (gate == 2) {
            acc = dotrange<BF>(wpv, wbase, c, 192, 320, rh4, 192, acc);
            // finish: h_new
            float hh = tanhf(acc);
            float z  = sh_z[jp];
            float hp = sh_kx[768 + js*128 + jp];
            float hn = z*hp + (1.f - z)*hh;
            stA(&hG[b*HHH + js*128 + jp], hn);
            out[((size_t)b*TDEC + t)*HHH + js*128 + jp] = hn;
            float p = sh_u[jp] * hn;
            float s = wave_sum(p);
            if ((tid & 63) == 0) sh_red[w] = s;             // waves 4,5
        }
        drain_stores();                                     // ALL waves drain h stores
        __syncthreads();
        if (tid == 0) {
            stA(&hdotP[t*256 + b*4 + js], sh_red[4] + sh_red[5]);
            arrive(&cnt[(t*3 + 2)*64 + b]);                 // event C: h + hdot ready
        }
    }
}

extern "C" void kernel_launch(void* const* d_in, const int* in_sizes, int n_in,
                              void* d_out, int out_size, void* d_ws, size_t ws_size,
                              hipStream_t stream) {
    const float* inputs = (const float*)d_in[0];
    const float* C      = (const float*)d_in[1];
    const float* w1     = (const float*)d_in[2];
    const float* w2     = (const float*)d_in[3];
    const float* Wx     = (const float*)d_in[4];
    const float* Wh     = (const float*)d_in[5];
    const float* bias   = (const float*)d_in[6];
    float* out = (float*)d_out;
    float* ws  = (float*)d_ws;

    hipMemsetAsync(ws, 0, 128*3*64*sizeof(unsigned), stream);

    k_u   <<<1024, 64,  0, stream>>>(w1, w2, ws + OFF_U);
    k_ectx<<<(64*TENC)/4, 256, 0, stream>>>(C, ws + OFF_U, ws + OFF_ECTX);

    const size_t need_f32 = (size_t)(OFF_WP) * 4u + (size_t)WP_ELEMS * 4u;
    void* wp = (void*)(ws + OFF_WP);
    if (ws_size >= need_f32) {
        k_wpack<false><<<WP_ELEMS/256, 256, 0, stream>>>(Wx, Wh, wp);
        decoder<false><<<NBLK, NTHR, 0, stream>>>(inputs, C, bias, wp,
                                                  ws + OFF_U, ws + OFF_ECTX, out, ws);
    } else {
        k_wpack<true><<<WP_ELEMS/256, 256, 0, stream>>>(Wx, Wh, wp);
        decoder<true><<<NBLK, NTHR, 0, stream>>>(inputs, C, bias, wp,
                                                 ws + OFF_U, ws + OFF_ECTX, out, ws);
    }
}